// Round 12
// baseline (645.596 us; speedup 1.0000x reference)
//
#include <hip/hip_runtime.h>

#define OUT_DIM 128
#define CHUNK_LG 15
#define CHUNK (1 << CHUNK_LG)   // 32768 nodes per chunk = 128 KB LDS
#define PB 64                   // blocks per chunk in chunkmax / partials depth
#define NCH_MAX 4               // N <= 2^17
#define BINB 512                // bin blocks (x4 waves = 2048 waves)

typedef int          vint4  __attribute__((ext_vector_type(4)));
typedef unsigned int vuint4 __attribute__((ext_vector_type(4)));
typedef unsigned int u32;
typedef unsigned long long u64;

// Round-to-nearest bf16 of d>=0, keep low 15 bits (sign always 0).
// Order-preserving for d>=0. enc15(0)=0.
__device__ __forceinline__ u32 enc15(float d) {
    u32 b = __float_as_uint(d);
    b += 0x7FFFu + ((b >> 16) & 1u);
    return (b >> 16) & 0x7FFFu;
}

// --- kernel 1: p[i] = nodes[i]·W_theta ; meanW ; zero bucket cursors
__global__ void init_kernel(float* __restrict__ p, float* __restrict__ meanW,
                            u32* __restrict__ gcur,
                            const float* __restrict__ nodes,
                            const float* __restrict__ Wt,
                            const float* __restrict__ W_phi, int n) {
    int i = blockIdx.x * blockDim.x + threadIdx.x;
    if (i < n) {
        float x = nodes[3 * i], y = nodes[3 * i + 1], z = nodes[3 * i + 2];
        p[i] = x * Wt[0] + y * Wt[1] + z * Wt[2];
    }
    if (blockIdx.x == 0) {
        if (threadIdx.x < NCH_MAX) gcur[threadIdx.x] = 0;  // re-zero every launch (graph replay)
        if (threadIdx.x == 0) {
            float s = 0.0f;
            #pragma unroll
            for (int j = 0; j < OUT_DIM; ++j) s += W_phi[j];
            *meanW = s / (float)OUT_DIM;
        }
    }
}

// --- kernel 2: fused encode + 4-way split. Per-wave 4x128-word circular LDS
// buffers; ballot-compaction appends (VGPR cursors, unrolled -> no scratch);
// full 64-word line flush with ONE lane0 atomicAdd per line (1 atomic / 64
// keys). Bucket content order is nondeterministic -> erased by max-reduce.
__global__ __launch_bounds__(256) void bin_kernel(const float* __restrict__ p,
                                                  const int* __restrict__ row,
                                                  const int* __restrict__ col,
                                                  u32* __restrict__ bkt,
                                                  u32* __restrict__ gcur,
                                                  int E, int cap) {
    __shared__ u32 buf[4][NCH_MAX][128];   // [wave][chunk][slot]
    int w    = (int)(threadIdx.x >> 6);
    int lane = (int)(threadIdx.x & 63);
    int gw   = blockIdx.x * 4 + w;         // global wave id, 0..BINB*4-1
    const int NW = BINB * 4;

    // contiguous per-wave edge range
    int perW = (E + NW - 1) / NW;
    int s0 = gw * perW;
    int e0 = min(s0 + perW, E);
    int myCnt = e0 - s0;
    int rounds = (myCnt + 63) / 64;

    u32 cur[NCH_MAX], fl[NCH_MAX];
    #pragma unroll
    for (int c = 0; c < NCH_MAX; ++c) { cur[c] = 0; fl[c] = 0; }
    u64 ltmask = ((u64)1 << lane) - 1;

    // 1-ahead index prefetch
    int rrN = 0, ccN = 0;
    {
        int i = s0 + lane;
        if (i < e0) { rrN = __builtin_nontemporal_load(row + i);
                      ccN = __builtin_nontemporal_load(col + i); }
    }

    for (int r = 0; r < rounds; ++r) {
        int i = s0 + r * 64 + lane;
        bool act = i < e0;
        int rr = rrN, cc = ccN;
        int i2 = i + 64;
        if (r + 1 < rounds && i2 < e0) {
            rrN = __builtin_nontemporal_load(row + i2);
            ccN = __builtin_nontemporal_load(col + i2);
        }
        u32 key = 0; int cl = -1;
        if (act) {
            key = ((u32)rr << 15) | enc15(fabsf(p[rr] - p[cc]));
            cl = rr >> CHUNK_LG;
        }
        #pragma unroll
        for (int c = 0; c < NCH_MAX; ++c) {
            u64 m = __ballot(cl == c);
            if (m) {
                if (cl == c) {
                    int off = (int)__popcll(m & ltmask);
                    buf[w][c][(cur[c] + off) & 127] = key;
                }
                cur[c] += (u32)__popcll(m);          // wave-uniform
                if (cur[c] - fl[c] >= 64) {          // uniform -> no divergence
                    u32 gb = 0;
                    if (lane == 0) gb = atomicAdd(&gcur[c], 64u);
                    gb = (u32)__shfl((int)gb, 0);
                    u32 v = buf[w][c][(fl[c] & 127) + lane];   // contiguous 64, no wrap
                    bkt[(size_t)c * cap + gb + lane] = v;
                    fl[c] += 64;
                }
            }
        }
    }
    // tail: flush remainders (<64 words) per chunk
    #pragma unroll
    for (int c = 0; c < NCH_MAX; ++c) {
        u32 rem = cur[c] - fl[c];
        if (rem) {
            u32 gb = 0;
            if (lane == 0) gb = atomicAdd(&gcur[c], rem);
            gb = (u32)__shfl((int)gb, 0);
            if ((u32)lane < rem)
                bkt[(size_t)c * cap + gb + lane] = buf[w][c][(fl[c] + lane) & 127];
        }
    }
}

// --- kernel 3: per-chunk LDS max over its bucket only; every key matches
// (no filter). 128 KB LDS, 512 threads, grid = nch*PB.
__global__ __launch_bounds__(512) void chunkmax_kernel(const u32* __restrict__ bkt,
                                                       const u32* __restrict__ gcur,
                                                       u32* __restrict__ partial,
                                                       int cap) {
    __shared__ u32 lds[CHUNK];
    int c = blockIdx.x / PB;
    int b = blockIdx.x % PB;
    vuint4 zero = {0u, 0u, 0u, 0u};
    vuint4* lds4 = (vuint4*)lds;
    for (int i = threadIdx.x; i < CHUNK / 4; i += 512) lds4[i] = zero;
    __syncthreads();

    int cnt = (int)gcur[c];
    const u32* bk = bkt + (size_t)c * cap;
    int per = (((cnt + PB - 1) / PB) + 3) & ~3;    // 4-aligned slices
    int s = b * per;
    int e = min(s + per, cnt);

    if (s < e) {
        int nv4 = (e - s) >> 2;
        const vuint4* bk4 = (const vuint4*)(bk + s);
        const int step = 512;
        int k = (int)threadIdx.x;
        for (; k + step < nv4; k += 2 * step) {
            vuint4 a0 = bk4[k];
            vuint4 a1 = bk4[k + step];
            atomicMax(&lds[(a0.x >> 15) & (CHUNK - 1)], a0.x & 0x7FFFu);
            atomicMax(&lds[(a0.y >> 15) & (CHUNK - 1)], a0.y & 0x7FFFu);
            atomicMax(&lds[(a0.z >> 15) & (CHUNK - 1)], a0.z & 0x7FFFu);
            atomicMax(&lds[(a0.w >> 15) & (CHUNK - 1)], a0.w & 0x7FFFu);
            atomicMax(&lds[(a1.x >> 15) & (CHUNK - 1)], a1.x & 0x7FFFu);
            atomicMax(&lds[(a1.y >> 15) & (CHUNK - 1)], a1.y & 0x7FFFu);
            atomicMax(&lds[(a1.z >> 15) & (CHUNK - 1)], a1.z & 0x7FFFu);
            atomicMax(&lds[(a1.w >> 15) & (CHUNK - 1)], a1.w & 0x7FFFu);
        }
        for (; k < nv4; k += step) {
            vuint4 a0 = bk4[k];
            atomicMax(&lds[(a0.x >> 15) & (CHUNK - 1)], a0.x & 0x7FFFu);
            atomicMax(&lds[(a0.y >> 15) & (CHUNK - 1)], a0.y & 0x7FFFu);
            atomicMax(&lds[(a0.z >> 15) & (CHUNK - 1)], a0.z & 0x7FFFu);
            atomicMax(&lds[(a0.w >> 15) & (CHUNK - 1)], a0.w & 0x7FFFu);
        }
        for (int j = s + (nv4 << 2) + (int)threadIdx.x; j < e; j += step) {
            u32 v = bk[j];
            atomicMax(&lds[(v >> 15) & (CHUNK - 1)], v & 0x7FFFu);
        }
    }
    __syncthreads();
    u32* dst = partial + ((size_t)c * PB + b) * (CHUNK / 2);
    for (int j = threadIdx.x; j < CHUNK / 2; j += 512)
        dst[j] = lds[2 * j] | (lds[2 * j + 1] << 16);
}

// --- kernel 4: reduce PB packed partials per chunk + final combine
__global__ void reduce_final_kernel(const float* __restrict__ prev,
                                    const u32* __restrict__ partial,
                                    const float* __restrict__ meanW,
                                    float* __restrict__ out, int n) {
    int t = blockIdx.x * blockDim.x + threadIdx.x;
    int i0 = t * 2;
    if (i0 >= n) return;
    int chunk = i0 >> CHUNK_LG;
    int local = i0 & (CHUNK - 1);            // even
    const u32* base = partial + (size_t)chunk * PB * (CHUNK / 2) + (local >> 1);
    u32 mlo = 0, mhi = 0;
    #pragma unroll
    for (int b = 0; b < PB; ++b) {
        u32 v = base[(size_t)b * (CHUNK / 2)];
        mlo = max(mlo, v & 0xFFFFu);
        mhi = max(mhi, v >> 16);
    }
    float mw = *meanW;
    float flo = __uint_as_float(mlo << 16);  // decode bf16 (sign 0)
    float fhi = __uint_as_float(mhi << 16);
    out[i0] = 0.5f * (prev[i0] + mw * flo);
    if (i0 + 1 < n)
        out[i0 + 1] = 0.5f * (prev[i0 + 1] + mw * fhi);
}

// ---------- fallback path: global-atomic version (any size) ----------
__global__ void fb_zero_kernel(float* __restrict__ maxd, float* __restrict__ p,
                               float* __restrict__ meanW,
                               const float* __restrict__ nodes,
                               const float* __restrict__ Wt,
                               const float* __restrict__ W_phi, int n) {
    int i = blockIdx.x * blockDim.x + threadIdx.x;
    if (i < n) {
        maxd[i] = 0.0f;
        float x = nodes[3 * i], y = nodes[3 * i + 1], z = nodes[3 * i + 2];
        p[i] = x * Wt[0] + y * Wt[1] + z * Wt[2];
    }
    if (blockIdx.x == 0 && threadIdx.x == 0) {
        float s = 0.0f;
        for (int j = 0; j < OUT_DIM; ++j) s += W_phi[j];
        *meanW = s / (float)OUT_DIM;
    }
}
__global__ void fb_edge_kernel(const float* __restrict__ p,
                               const int* __restrict__ row,
                               const int* __restrict__ col,
                               float* __restrict__ maxd, int E) {
    int t = blockIdx.x * blockDim.x + threadIdx.x;
    int base = t * 4;
    if (base >= E) return;
    if (base + 3 < E) {
        vint4 r = __builtin_nontemporal_load((const vint4*)(row + base));
        vint4 c = __builtin_nontemporal_load((const vint4*)(col + base));
        atomicMax((int*)&maxd[r.x], __float_as_int(fabsf(p[r.x] - p[c.x])));
        atomicMax((int*)&maxd[r.y], __float_as_int(fabsf(p[r.y] - p[c.y])));
        atomicMax((int*)&maxd[r.z], __float_as_int(fabsf(p[r.z] - p[c.z])));
        atomicMax((int*)&maxd[r.w], __float_as_int(fabsf(p[r.w] - p[c.w])));
    } else {
        for (int e = base; e < E; ++e) {
            float d = fabsf(p[row[e]] - p[col[e]]);
            atomicMax((int*)&maxd[row[e]], __float_as_int(d));
        }
    }
}
__global__ void fb_final_kernel(const float* __restrict__ prev,
                                const float* __restrict__ maxd,
                                const float* __restrict__ meanW,
                                float* __restrict__ out, int n) {
    int i = blockIdx.x * blockDim.x + threadIdx.x;
    if (i < n) out[i] = 0.5f * (prev[i] + (*meanW) * maxd[i]);
}

extern "C" void kernel_launch(void* const* d_in, const int* in_sizes, int n_in,
                              void* d_out, int out_size, void* d_ws, size_t ws_size,
                              hipStream_t stream) {
    const float* prev    = (const float*)d_in[0];   // [N]
    const float* nodes   = (const float*)d_in[1];   // [N,3]
    const int*   row     = (const int*)d_in[2];     // [E]
    const int*   col     = (const int*)d_in[3];     // [E]
    const float* W_phi   = (const float*)d_in[4];   // [128]
    const float* W_theta = (const float*)d_in[5];   // [3]

    const int N = in_sizes[0];
    const int E = in_sizes[2];
    float* out = (float*)d_out;
    const int B = 256;

    const int nch = (N + CHUNK - 1) >> CHUNK_LG;    // <=4 for N<=2^17
    const int cap = (E + 1024) & ~255;              // bucket stride (words)

    // ws layout: p[N] | bkt[4*cap] | partial[nch*PB*CHUNK/2] | gcur[4] | meanW
    size_t pBytes    = ((size_t)N * 4 + 255) & ~(size_t)255;
    size_t bktBytes  = (size_t)NCH_MAX * cap * 4;
    size_t partBytes = (size_t)nch * PB * (CHUNK / 2) * 4;
    size_t need = pBytes + bktBytes + partBytes + NCH_MAX * 4 + 4;

    if (ws_size >= need && N <= (1 << 17)) {
        float* p     = (float*)d_ws;
        u32*   bkt   = (u32*)((char*)d_ws + pBytes);
        u32*   part  = (u32*)((char*)d_ws + pBytes + bktBytes);
        u32*   gcur  = (u32*)((char*)d_ws + pBytes + bktBytes + partBytes);
        float* meanW = (float*)((char*)d_ws + pBytes + bktBytes + partBytes + NCH_MAX * 4);

        init_kernel<<<(N + B - 1) / B, B, 0, stream>>>(p, meanW, gcur, nodes, W_theta, W_phi, N);
        bin_kernel<<<BINB, 256, 0, stream>>>(p, row, col, bkt, gcur, E, cap);
        chunkmax_kernel<<<nch * PB, 512, 0, stream>>>(bkt, gcur, part, cap);
        int tN = (N + 1) / 2;
        reduce_final_kernel<<<(tN + B - 1) / B, B, 0, stream>>>(prev, part, meanW, out, N);
    } else {
        float* p     = (float*)d_ws;
        float* maxd  = (float*)d_ws + N;
        float* meanW = (float*)d_ws + 2 * (size_t)N;
        fb_zero_kernel<<<(N + B - 1) / B, B, 0, stream>>>(maxd, p, meanW, nodes, W_theta, W_phi, N);
        int tE = (E + 3) / 4;
        fb_edge_kernel<<<(tE + B - 1) / B, B, 0, stream>>>(p, row, col, maxd, E);
        fb_final_kernel<<<(N + B - 1) / B, B, 0, stream>>>(prev, maxd, meanW, out, N);
    }
}

// Round 13
// 69.596 us; speedup vs baseline: 9.2763x; 9.2763x over previous
//
#include <hip/hip_runtime.h>

#define OUT_DIM 128
#define CHUNK_LG 15
#define CHUNK (1 << CHUNK_LG)   // 32768 nodes per chunk = 128 KB LDS
#define PB 64                   // blocks per chunk in chunkmax / partials depth
#define NCH_MAX 4               // N <= 2^17
#define BINB 1024               // bin blocks (x4 waves = 4096 waves)
#define NW (BINB * 4)

typedef int          vint4  __attribute__((ext_vector_type(4)));
typedef unsigned int vuint4 __attribute__((ext_vector_type(4)));
typedef unsigned int u32;
typedef unsigned long long u64;

// Round-to-nearest bf16 of d>=0, keep low 15 bits (sign always 0).
// Order-preserving for d>=0. enc15(0)=0.
__device__ __forceinline__ u32 enc15(float d) {
    u32 b = __float_as_uint(d);
    b += 0x7FFFu + ((b >> 16) & 1u);
    return (b >> 16) & 0x7FFFu;
}

// --- kernel 1: p[i] = nodes[i]·W_theta ; meanW = mean(W_phi)
__global__ void init_kernel(float* __restrict__ p, float* __restrict__ meanW,
                            const float* __restrict__ nodes,
                            const float* __restrict__ Wt,
                            const float* __restrict__ W_phi, int n) {
    int i = blockIdx.x * blockDim.x + threadIdx.x;
    if (i < n) {
        float x = nodes[3 * i], y = nodes[3 * i + 1], z = nodes[3 * i + 2];
        p[i] = x * Wt[0] + y * Wt[1] + z * Wt[2];
    }
    if (blockIdx.x == 0 && threadIdx.x == 0) {
        float s = 0.0f;
        #pragma unroll
        for (int j = 0; j < OUT_DIM; ++j) s += W_phi[j];
        *meanW = s / (float)OUT_DIM;
    }
}

// --- kernel 2: fused encode + 4-way split, ZERO global atomics.
// Per-wave 4x128-word circular LDS buffers; ballot-compaction appends
// (VGPR cursors, fully unrolled); when a buffer holds >=64 words, flush one
// full 256B line to this wave's STATIC region (bkt + (gw*4+c)*capWC + fl).
// No return dependency, no shared cursors. Region order nondeterminism is
// erased by the downstream max-reduce. Capacity: cur[c] <= perW <= capWC.
__global__ __launch_bounds__(256) void bin_kernel(const float* __restrict__ p,
                                                  const int* __restrict__ row,
                                                  const int* __restrict__ col,
                                                  u32* __restrict__ bkt,
                                                  u32* __restrict__ cnt,
                                                  int E, int capWC) {
    __shared__ u32 buf[4][NCH_MAX][128];   // [wave][chunk][slot]
    int w    = (int)(threadIdx.x >> 6);
    int lane = (int)(threadIdx.x & 63);
    int gw   = blockIdx.x * 4 + w;         // global wave id, 0..NW-1

    int perW = (E + NW - 1) / NW;
    int s0 = gw * perW;
    int e0 = min(s0 + perW, E);
    int rounds = (max(0, e0 - s0) + 63) / 64;

    u32 cur[NCH_MAX], fl[NCH_MAX];
    #pragma unroll
    for (int c = 0; c < NCH_MAX; ++c) { cur[c] = 0; fl[c] = 0; }
    u64 ltmask = ((u64)1 << lane) - 1;

    // 1-ahead index prefetch
    int rrN = 0, ccN = 0;
    {
        int i = s0 + lane;
        if (i < e0) { rrN = __builtin_nontemporal_load(row + i);
                      ccN = __builtin_nontemporal_load(col + i); }
    }

    for (int r = 0; r < rounds; ++r) {
        int i = s0 + r * 64 + lane;
        bool act = i < e0;
        int rr = rrN, cc = ccN;
        int i2 = i + 64;
        if (r + 1 < rounds && i2 < e0) {
            rrN = __builtin_nontemporal_load(row + i2);
            ccN = __builtin_nontemporal_load(col + i2);
        }
        u32 key = 0; int cl = -1;
        if (act) {
            key = ((u32)rr << 15) | enc15(fabsf(p[rr] - p[cc]));
            cl = rr >> CHUNK_LG;
        }
        #pragma unroll
        for (int c = 0; c < NCH_MAX; ++c) {
            u64 m = __ballot(cl == c);
            if (m) {                                  // wave-uniform
                if (cl == c) {
                    int off = (int)__popcll(m & ltmask);
                    buf[w][c][(cur[c] + off) & 127] = key;
                }
                cur[c] += (u32)__popcll(m);
                if (cur[c] - fl[c] >= 64) {           // at most once per round
                    u32* dst = bkt + ((size_t)gw * NCH_MAX + c) * capWC + fl[c];
                    dst[lane] = buf[w][c][(fl[c] & 127) + lane];  // full line, no wrap
                    fl[c] += 64;
                }
            }
        }
    }
    // tail: flush remainders (<64 words) per chunk
    #pragma unroll
    for (int c = 0; c < NCH_MAX; ++c) {
        u32 rem = cur[c] - fl[c];
        if (rem) {
            u32* dst = bkt + ((size_t)gw * NCH_MAX + c) * capWC + fl[c];
            if ((u32)lane < rem)
                dst[lane] = buf[w][c][(fl[c] + lane) & 127];
        }
        if (lane == 0) cnt[(size_t)gw * NCH_MAX + c] = cur[c];
    }
}

// --- kernel 3: per-chunk LDS max; each key read exactly once, NO filter.
// grid = nch*PB, 512 threads (8 waves), 128 KB LDS. Block (c,b) covers
// region set {w : w in [b*R, (b+1)*R)}, R = NW/PB; wave v takes every 8th.
__global__ __launch_bounds__(512) void chunkmax_kernel(const u32* __restrict__ bkt,
                                                       const u32* __restrict__ cnt,
                                                       u32* __restrict__ partial,
                                                       int capWC) {
    __shared__ u32 lds[CHUNK];
    int c = blockIdx.x / PB;
    int b = blockIdx.x % PB;
    vuint4 zero = {0u, 0u, 0u, 0u};
    vuint4* lds4 = (vuint4*)lds;
    for (int i = threadIdx.x; i < CHUNK / 4; i += 512) lds4[i] = zero;
    __syncthreads();

    const int R = NW / PB;                 // regions per block (64)
    int wave = (int)(threadIdx.x >> 6);
    int lane = (int)(threadIdx.x & 63);
    int w0 = b * R;
    for (int w = w0 + wave; w < w0 + R; w += 8) {
        int n = (int)cnt[(size_t)w * NCH_MAX + c];
        const u32* reg = bkt + ((size_t)w * NCH_MAX + c) * capWC;
        int nv4 = n >> 2;
        const vuint4* reg4 = (const vuint4*)reg;   // capWC%4==0 -> 16B aligned
        for (int g = lane; g < nv4; g += 64) {
            vuint4 a = reg4[g];
            atomicMax(&lds[(a.x >> 15) & (CHUNK - 1)], a.x & 0x7FFFu);
            atomicMax(&lds[(a.y >> 15) & (CHUNK - 1)], a.y & 0x7FFFu);
            atomicMax(&lds[(a.z >> 15) & (CHUNK - 1)], a.z & 0x7FFFu);
            atomicMax(&lds[(a.w >> 15) & (CHUNK - 1)], a.w & 0x7FFFu);
        }
        int t0 = nv4 << 2;
        if (lane < (n - t0)) {
            u32 v = reg[t0 + lane];
            atomicMax(&lds[(v >> 15) & (CHUNK - 1)], v & 0x7FFFu);
        }
    }
    __syncthreads();
    u32* dst = partial + ((size_t)c * PB + b) * (CHUNK / 2);
    for (int j = threadIdx.x; j < CHUNK / 2; j += 512)
        dst[j] = lds[2 * j] | (lds[2 * j + 1] << 16);
}

// --- kernel 4: reduce PB packed partials per chunk + final combine
__global__ void reduce_final_kernel(const float* __restrict__ prev,
                                    const u32* __restrict__ partial,
                                    const float* __restrict__ meanW,
                                    float* __restrict__ out, int n) {
    int t = blockIdx.x * blockDim.x + threadIdx.x;
    int i0 = t * 2;
    if (i0 >= n) return;
    int chunk = i0 >> CHUNK_LG;
    int local = i0 & (CHUNK - 1);            // even
    const u32* base = partial + (size_t)chunk * PB * (CHUNK / 2) + (local >> 1);
    u32 mlo = 0, mhi = 0;
    #pragma unroll
    for (int b = 0; b < PB; ++b) {
        u32 v = base[(size_t)b * (CHUNK / 2)];
        mlo = max(mlo, v & 0xFFFFu);
        mhi = max(mhi, v >> 16);
    }
    float mw = *meanW;
    float flo = __uint_as_float(mlo << 16);  // decode bf16 (sign 0)
    float fhi = __uint_as_float(mhi << 16);
    out[i0] = 0.5f * (prev[i0] + mw * flo);
    if (i0 + 1 < n)
        out[i0 + 1] = 0.5f * (prev[i0 + 1] + mw * fhi);
}

// ---------- fallback path: global-atomic version (any size) ----------
__global__ void fb_zero_kernel(float* __restrict__ maxd, float* __restrict__ p,
                               float* __restrict__ meanW,
                               const float* __restrict__ nodes,
                               const float* __restrict__ Wt,
                               const float* __restrict__ W_phi, int n) {
    int i = blockIdx.x * blockDim.x + threadIdx.x;
    if (i < n) {
        maxd[i] = 0.0f;
        float x = nodes[3 * i], y = nodes[3 * i + 1], z = nodes[3 * i + 2];
        p[i] = x * Wt[0] + y * Wt[1] + z * Wt[2];
    }
    if (blockIdx.x == 0 && threadIdx.x == 0) {
        float s = 0.0f;
        for (int j = 0; j < OUT_DIM; ++j) s += W_phi[j];
        *meanW = s / (float)OUT_DIM;
    }
}
__global__ void fb_edge_kernel(const float* __restrict__ p,
                               const int* __restrict__ row,
                               const int* __restrict__ col,
                               float* __restrict__ maxd, int E) {
    int t = blockIdx.x * blockDim.x + threadIdx.x;
    int base = t * 4;
    if (base >= E) return;
    if (base + 3 < E) {
        vint4 r = __builtin_nontemporal_load((const vint4*)(row + base));
        vint4 c = __builtin_nontemporal_load((const vint4*)(col + base));
        atomicMax((int*)&maxd[r.x], __float_as_int(fabsf(p[r.x] - p[c.x])));
        atomicMax((int*)&maxd[r.y], __float_as_int(fabsf(p[r.y] - p[c.y])));
        atomicMax((int*)&maxd[r.z], __float_as_int(fabsf(p[r.z] - p[c.z])));
        atomicMax((int*)&maxd[r.w], __float_as_int(fabsf(p[r.w] - p[c.w])));
    } else {
        for (int e = base; e < E; ++e) {
            float d = fabsf(p[row[e]] - p[col[e]]);
            atomicMax((int*)&maxd[row[e]], __float_as_int(d));
        }
    }
}
__global__ void fb_final_kernel(const float* __restrict__ prev,
                                const float* __restrict__ maxd,
                                const float* __restrict__ meanW,
                                float* __restrict__ out, int n) {
    int i = blockIdx.x * blockDim.x + threadIdx.x;
    if (i < n) out[i] = 0.5f * (prev[i] + (*meanW) * maxd[i]);
}

extern "C" void kernel_launch(void* const* d_in, const int* in_sizes, int n_in,
                              void* d_out, int out_size, void* d_ws, size_t ws_size,
                              hipStream_t stream) {
    const float* prev    = (const float*)d_in[0];   // [N]
    const float* nodes   = (const float*)d_in[1];   // [N,3]
    const int*   row     = (const int*)d_in[2];     // [E]
    const int*   col     = (const int*)d_in[3];     // [E]
    const float* W_phi   = (const float*)d_in[4];   // [128]
    const float* W_theta = (const float*)d_in[5];   // [3]

    const int N = in_sizes[0];
    const int E = in_sizes[2];
    float* out = (float*)d_out;
    const int B = 256;

    const int nch = (N + CHUNK - 1) >> CHUNK_LG;    // <=4 for N<=2^17
    const int perW = (E + NW - 1) / NW;
    const int capWC = ((perW + 63) / 64) * 64;      // per-(wave,chunk) region words

    // ws layout: p[N] | bkt[NW*4*capWC] | cnt[NW*4] | partial | meanW
    size_t pBytes    = ((size_t)N * 4 + 255) & ~(size_t)255;
    size_t bktBytes  = (size_t)NW * NCH_MAX * capWC * 4;
    size_t cntBytes  = ((size_t)NW * NCH_MAX * 4 + 255) & ~(size_t)255;
    size_t partBytes = (size_t)nch * PB * (CHUNK / 2) * 4;
    size_t need = pBytes + bktBytes + cntBytes + partBytes + 4;

    if (ws_size >= need && N <= (1 << 17)) {
        float* p     = (float*)d_ws;
        u32*   bkt   = (u32*)((char*)d_ws + pBytes);
        u32*   cnt   = (u32*)((char*)d_ws + pBytes + bktBytes);
        u32*   part  = (u32*)((char*)d_ws + pBytes + bktBytes + cntBytes);
        float* meanW = (float*)((char*)d_ws + pBytes + bktBytes + cntBytes + partBytes);

        init_kernel<<<(N + B - 1) / B, B, 0, stream>>>(p, meanW, nodes, W_theta, W_phi, N);
        bin_kernel<<<BINB, 256, 0, stream>>>(p, row, col, bkt, cnt, E, capWC);
        chunkmax_kernel<<<nch * PB, 512, 0, stream>>>(bkt, cnt, part, capWC);
        int tN = (N + 1) / 2;
        reduce_final_kernel<<<(tN + B - 1) / B, B, 0, stream>>>(prev, part, meanW, out, N);
    } else {
        float* p     = (float*)d_ws;
        float* maxd  = (float*)d_ws + N;
        float* meanW = (float*)d_ws + 2 * (size_t)N;
        fb_zero_kernel<<<(N + B - 1) / B, B, 0, stream>>>(maxd, p, meanW, nodes, W_theta, W_phi, N);
        int tE = (E + 3) / 4;
        fb_edge_kernel<<<(tE + B - 1) / B, B, 0, stream>>>(p, row, col, maxd, E);
        fb_final_kernel<<<(N + B - 1) / B, B, 0, stream>>>(prev, maxd, meanW, out, N);
    }
}